// Round 7
// baseline (316.023 us; speedup 1.0000x reference)
//
#include <hip/hip_runtime.h>
#include <math.h>

#define NB 4
#define NN 4096
#define KSEL 204
#define NBINS 512
#define CANDN 256
#define QKSCALE 0.31622776601683794f

// workspace layout in floats
#define WS_Q 0
#define WS_KT (NB * NN * 10)       // 163840
#define WS_V (2 * NB * NN * 10)    // 327680
#define WS_LG (3 * NB * NN * 10)   // 491520  (+ NB*NN*2 = 32768)

#define SEQ_PER_BLOCK 16

// kT layout: [B][10][N] row-major (the [B][N/64][10][64] variant broke L2
// write-combining of out_probs -> 14x WRITE_SIZE; keep row-major).

__global__ __launch_bounds__(256) void featqkv_kernel(
    const float* __restrict__ x,
    const float* __restrict__ w2, const float* __restrict__ b2,
    const float* __restrict__ w3, const float* __restrict__ b3,
    const float* __restrict__ w4, const float* __restrict__ b4,
    const float* __restrict__ w5, const float* __restrict__ b5,
    const float* __restrict__ w6, const float* __restrict__ b6,
    const float* __restrict__ w7, const float* __restrict__ b7,
    const float* __restrict__ wq, const float* __restrict__ bq,
    const float* __restrict__ wk, const float* __restrict__ bk,
    const float* __restrict__ wv, const float* __restrict__ bv,
    float* __restrict__ q_out, float* __restrict__ kT_out, float* __restrict__ v_out)
{
    __shared__ __align__(16) float xs[SEQ_PER_BLOCK * 360];
    __shared__ float wpad[14 * 105];   // zero-padded to 7 taps: [ch][c=15][j=7]
    __shared__ float bconv[14];
    __shared__ float wqkv[420];
    __shared__ float bqkv[30];
    __shared__ float feats[SEQ_PER_BLOCK * 14];

    const int t = threadIdx.x;
    const int g0 = blockIdx.x * SEQ_PER_BLOCK;

    // ---- stage x as float4 ----
    {
        const float4* xg4 = reinterpret_cast<const float4*>(x + (size_t)g0 * 360);
        float4* xs4 = reinterpret_cast<float4*>(xs);
        for (int i = t; i < SEQ_PER_BLOCK * 90; i += 256) xs4[i] = xg4[i];
    }

    // ---- stage conv weights, zero-padded to uniform 7 taps ----
    for (int i = t; i < 14 * 105; i += 256) {
        const int ch = i / 105;
        const int r = i - ch * 105;
        const int c = r / 7;
        const int j = r - (r / 7) * 7;
        float val = 0.f;
        if (ch < 3)       { if (j < 2) val = w2[ch * 30 + c * 2 + j]; }
        else if (ch < 6)  { if (j < 3) val = w3[(ch - 3) * 45 + c * 3 + j]; }
        else if (ch < 9)  { if (j < 4) val = w4[(ch - 6) * 60 + c * 4 + j]; }
        else if (ch < 11) { if (j < 5) val = w5[(ch - 9) * 75 + c * 5 + j]; }
        else if (ch < 13) { if (j < 6) val = w6[(ch - 11) * 90 + c * 6 + j]; }
        else              { val = w7[c * 7 + j]; }
        wpad[i] = val;
    }
    if (t < 3) bconv[t] = b2[t];
    else if (t < 6) bconv[t] = b3[t - 3];
    else if (t < 9) bconv[t] = b4[t - 6];
    else if (t < 11) bconv[t] = b5[t - 9];
    else if (t < 13) bconv[t] = b6[t - 11];
    else if (t == 13) bconv[t] = b7[0];
    for (int i = t; i < 140; i += 256) wqkv[i] = wq[i];
    for (int i = t; i < 140; i += 256) wqkv[140 + i] = wk[i];
    for (int i = t; i < 140; i += 256) wqkv[280 + i] = wv[i];
    if (t < 10) bqkv[t] = bq[t];
    else if (t < 20) bqkv[t] = bk[t - 10];
    else if (t < 30) bqkv[t] = bv[t - 20];
    __syncthreads();

    const int seq = t >> 4;
    const int wkr = t & 15;

    if (wkr < 14) {
        const int ch = wkr;
        int T;
        if (ch < 3) T = 23; else if (ch < 6) T = 22; else if (ch < 9) T = 21;
        else if (ch < 11) T = 20; else if (ch < 13) T = 19; else T = 18;

        float acc[23];
#pragma unroll
        for (int u = 0; u < 23; u++) acc[u] = 0.f;
        const float* xrow = &xs[seq * 360];
        const float* wrow = &wpad[ch * 105];
        for (int c = 0; c < 15; c++) {
            float xr[30];
            const float4* xp = reinterpret_cast<const float4*>(xrow + c * 24);
#pragma unroll
            for (int u4 = 0; u4 < 6; u4++) {
                const float4 xv = xp[u4];
                xr[u4 * 4 + 0] = xv.x; xr[u4 * 4 + 1] = xv.y;
                xr[u4 * 4 + 2] = xv.z; xr[u4 * 4 + 3] = xv.w;
            }
#pragma unroll
            for (int u = 24; u < 30; u++) xr[u] = 0.f;
#pragma unroll
            for (int j = 0; j < 7; j++) {
                const float wv_ = wrow[c * 7 + j];
#pragma unroll
                for (int tt = 0; tt < 23; tt++)
                    acc[tt] = fmaf(xr[tt + j], wv_, acc[tt]);
            }
        }
        float m = -3.0e38f;
#pragma unroll
        for (int tt = 0; tt < 23; tt++)
            if (tt < T) m = fmaxf(m, acc[tt]);
        feats[seq * 14 + ch] = fmaxf(m + bconv[ch], 0.f);
    }
    __syncthreads();

    const int g = g0 + seq;
    const int b_ = g >> 12;
    const int n_ = g & 4095;
    for (int o = wkr; o < 30; o += 16) {
        const int type = o / 10;
        const int comp = o % 10;
        const float* wrow = &wqkv[type * 140 + comp * 14];
        const float* frow = &feats[seq * 14];
        float a = bqkv[type * 10 + comp];
#pragma unroll
        for (int ii = 0; ii < 14; ii++) a = fmaf(frow[ii], wrow[ii], a);
        if (type == 0) q_out[(size_t)g * 10 + comp] = a;
        else if (type == 1) kT_out[((size_t)b_ * 10 + comp) * NN + n_] = a;
        else v_out[(size_t)g * 10 + comp] = a;
    }
}

__device__ __forceinline__ float dec_key(unsigned int k) {
    return (k & 0x80000000u) ? __uint_as_float(k ^ 0x80000000u)
                             : __uint_as_float(~k);
}
__device__ __forceinline__ unsigned int enc_key(float s) {
    unsigned int u = __float_as_uint(s);
    return (u & 0x80000000u) ? ~u : (u | 0x80000000u);
}
__device__ __forceinline__ int binof(float s, float lo, float scale) {
    return (int)fminf((s - lo) * scale, (float)(NBINS - 1));
}

// ONE WAVE PER ROW, 4 rows (4 waves) per 256-thread block.
// All phases wave-internal: shfl butterflies + wave-local LDS region.
// ZERO __syncthreads — only __threadfence_block() at LDS phase transitions.
// Each lane owns 64 keys (16 x float4), scores held in VGPRs.
__global__ __launch_bounds__(256) void attn_kernel(
    const float* __restrict__ qbuf, const float* __restrict__ kTbuf,
    const float* __restrict__ vbuf,
    const float* __restrict__ w_attn, const float* __restrict__ b_attn,
    const float* __restrict__ w_mil, const float* __restrict__ b_mil,
    float* __restrict__ out_probs, float* __restrict__ logits)
{
    __shared__ unsigned int base_[4][NBINS];       // pristine suffix counts
    __shared__ unsigned int bc_[4][NBINS];         // mutable scatter counters
    __shared__ unsigned long long cand[4][CANDN];  // candidate keys

    const int t = threadIdx.x;
    const int lane = t & 63;
    const int w = t >> 6;
    const int row = blockIdx.x * 4 + w;
    const int b_ = row >> 12;

    // ---- zero this wave's LDS region (wave-local; LDS pipe is in-order per wave) ----
#pragma unroll
    for (int i = 0; i < 8; i++) base_[w][lane + i * 64] = 0u;
#pragma unroll
    for (int i = 0; i < 4; i++) cand[w][lane + i * 64] = 0ULL;

    // ---- load q (5 x float2; rows are 40B so 8B-aligned) ----
    float qr[10];
    {
        const float2* qp2 = reinterpret_cast<const float2*>(qbuf + (size_t)row * 10);
        const float2 a = qp2[0], b = qp2[1], c = qp2[2], d = qp2[3], e = qp2[4];
        qr[0] = a.x; qr[1] = a.y; qr[2] = b.x; qr[3] = b.y; qr[4] = c.x;
        qr[5] = c.y; qr[6] = d.x; qr[7] = d.y; qr[8] = e.x; qr[9] = e.y;
    }

    // ---- P1: 64 scores per lane + running min/max ----
    const float* kTb = kTbuf + (size_t)b_ * 10 * NN;
    float sc[64];
    float vhi = -1e30f, vlo = 1e30f;
#pragma unroll
    for (int g = 0; g < 16; g++) {
        float ax = 0.f, ay = 0.f, az = 0.f, aw = 0.f;
#pragma unroll
        for (int c = 0; c < 10; c++) {
            const float4 kv = reinterpret_cast<const float4*>(kTb + c * NN)[g * 64 + lane];
            ax = fmaf(qr[c], kv.x, ax);
            ay = fmaf(qr[c], kv.y, ay);
            az = fmaf(qr[c], kv.z, az);
            aw = fmaf(qr[c], kv.w, aw);
        }
        sc[g * 4 + 0] = ax; sc[g * 4 + 1] = ay;
        sc[g * 4 + 2] = az; sc[g * 4 + 3] = aw;
        vhi = fmaxf(vhi, fmaxf(fmaxf(ax, ay), fmaxf(az, aw)));
        vlo = fminf(vlo, fminf(fminf(ax, ay), fminf(az, aw)));
    }
    // wave butterfly -> all lanes hold row min/max
#pragma unroll
    for (int off = 32; off > 0; off >>= 1) {
        vhi = fmaxf(vhi, __shfl_xor(vhi, off));
        vlo = fminf(vlo, __shfl_xor(vlo, off));
    }
    const float hi = vhi, lo = vlo;
    const bool degen = (hi <= lo);
    const float smax = hi * QKSCALE;

    float pv[4]; int pp[4], jj[4]; bool sel[4];
#pragma unroll
    for (int q = 0; q < 4; q++) { pv[q] = 0.f; pp[q] = 0; jj[q] = 0; sel[q] = false; }

    if (!degen) {
        const float scale = (float)(NBINS - 1) / (hi - lo);

        // ---- P2: histogram (wave-local atomics) ----
#pragma unroll
        for (int i = 0; i < 64; i++) {
            const int bin = binof(sc[i], lo, scale);
            atomicAdd(&base_[w][bin], 1u);
        }
        __threadfence_block();

        // ---- P3: suffix scan, 8 bins/lane ----
        {
            unsigned int c8[8];
            unsigned int T_ = 0u;
#pragma unroll
            for (int k = 0; k < 8; k++) { c8[k] = base_[w][lane * 8 + k]; T_ += c8[k]; }
            unsigned int acc = T_;
#pragma unroll
            for (int off = 1; off < 64; off <<= 1) {
                unsigned int o = __shfl_down(acc, off);
                if (lane + off < 64) acc += o;
            }
            unsigned int run = acc - T_;   // keys in bins owned by strictly-higher lanes
#pragma unroll
            for (int k = 7; k >= 0; k--) {
                base_[w][lane * 8 + k] = run;
                bc_[w][lane * 8 + k] = run;
                run += c8[k];
            }
        }
        __threadfence_block();

        // ---- P4: scatter candidate keys (bins whose suffix-base < KSEL) ----
#pragma unroll
        for (int i = 0; i < 64; i++) {
            const int bin = binof(sc[i], lo, scale);
            const unsigned int bs = base_[w][bin];
            if (bs < KSEL) {
                const unsigned int pos = atomicAdd(&bc_[w][bin], 1u);
                if (pos < CANDN) {
                    const int j = (i >> 2) * 256 + lane * 4 + (i & 3);
                    cand[w][pos] = (((unsigned long long)enc_key(sc[i])) << 16)
                                 | (unsigned long long)(4095 - j);
                }
            }
        }
        __threadfence_block();

        // ---- P5: within-bin rank -> exact sorted position (4 slots/lane) ----
#pragma unroll
        for (int q = 0; q < 4; q++) {
            const int s_idx = lane + 64 * q;
            const unsigned long long mine = cand[w][s_idx];
            if (mine != 0ULL) {
                const float s = dec_key((unsigned int)(mine >> 16));
                const int bin = binof(s, lo, scale);
                const unsigned int bs = base_[w][bin];
                unsigned int e2 = (bin > 0) ? base_[w][bin - 1] : 4096u;
                if (e2 > CANDN) e2 = CANDN;
                unsigned int rank = 0;
                for (unsigned int s2 = bs; s2 < e2; s2++)
                    rank += (cand[w][s2] > mine) ? 1u : 0u;
                const unsigned int pq = bs + rank;
                if (pq < KSEL) {
                    sel[q] = true;
                    pp[q] = (int)pq;
                    jj[q] = 4095 - (int)(mine & 0xFFFFu);
                    pv[q] = expf(s * QKSCALE - smax);
                }
            }
        }
    } else {
        // all scores equal: top-K = lowest 204 indices, uniform softmax
#pragma unroll
        for (int q = 0; q < 4; q++) {
            const int s_idx = lane + 64 * q;
            if (s_idx < KSEL) { sel[q] = true; pp[q] = s_idx; jj[q] = s_idx; pv[q] = 1.f; }
        }
    }

    // ---- P6: softmax denom (wave butterfly) ----
    float dsum = pv[0] + pv[1] + pv[2] + pv[3];
#pragma unroll
    for (int off = 32; off > 0; off >>= 1) dsum += __shfl_xor(dsum, off);
    const float inv = 1.f / dsum;

    // ---- P7: probs out + ctx accumulate (<=4 selections/lane) ----
    float cx[10];
#pragma unroll
    for (int d = 0; d < 10; d++) cx[d] = 0.f;
#pragma unroll
    for (int q = 0; q < 4; q++) {
        if (sel[q]) {
            const float pn = pv[q] * inv;
            out_probs[(size_t)row * KSEL + pp[q]] = pn;
            const float* vr = vbuf + ((size_t)b_ * NN + (size_t)jj[q]) * 10;
            const float2 v01 = reinterpret_cast<const float2*>(vr)[0];
            const float2 v23 = reinterpret_cast<const float2*>(vr)[1];
            const float2 v45 = reinterpret_cast<const float2*>(vr)[2];
            const float2 v67 = reinterpret_cast<const float2*>(vr)[3];
            const float2 v89 = reinterpret_cast<const float2*>(vr)[4];
            cx[0] = fmaf(pn, v01.x, cx[0]); cx[1] = fmaf(pn, v01.y, cx[1]);
            cx[2] = fmaf(pn, v23.x, cx[2]); cx[3] = fmaf(pn, v23.y, cx[3]);
            cx[4] = fmaf(pn, v45.x, cx[4]); cx[5] = fmaf(pn, v45.y, cx[5]);
            cx[6] = fmaf(pn, v67.x, cx[6]); cx[7] = fmaf(pn, v67.y, cx[7]);
            cx[8] = fmaf(pn, v89.x, cx[8]); cx[9] = fmaf(pn, v89.y, cx[9]);
        }
    }
    // wave butterfly: every lane ends with the full ctx vector
#pragma unroll
    for (int off = 32; off > 0; off >>= 1) {
#pragma unroll
        for (int d = 0; d < 10; d++) cx[d] += __shfl_xor(cx[d], off);
    }

    // ---- P8: attn projection + mil logits, all wave-internal ----
    float m0 = 0.f, m1 = 0.f;
    if (lane < 14) {
        float a = b_attn[lane];
#pragma unroll
        for (int d = 0; d < 10; d++) a = fmaf(cx[d], w_attn[lane * 10 + d], a);
        m0 = a * w_mil[lane];
        m1 = a * w_mil[14 + lane];
    }
    // reduce over the 16-lane group containing lanes 0..13
#pragma unroll
    for (int off = 8; off > 0; off >>= 1) {
        m0 += __shfl_xor(m0, off);
        m1 += __shfl_xor(m1, off);
    }
    if (lane == 0) {
        float2 lgv;
        lgv.x = m0 + b_mil[0];
        lgv.y = m1 + b_mil[1];
        *reinterpret_cast<float2*>(logits + (size_t)row * 2) = lgv;
    }
}

__global__ __launch_bounds__(256) void pool_kernel(
    const float* __restrict__ logits, float* __restrict__ out)
{
    __shared__ float red[256];
    const int t = threadIdx.x;
    const int bc = blockIdx.x;
    const int b_ = bc >> 1;
    const int c_ = bc & 1;
    float a = 0.f;
    for (int n2 = t; n2 < NN; n2 += 256)
        a += logits[((size_t)b_ * NN + n2) * 2 + c_];
    red[t] = a;
    __syncthreads();
    for (int off = 128; off > 0; off >>= 1) {
        if (t < off) red[t] += red[t + off];
        __syncthreads();
    }
    if (t == 0) out[bc] = red[0] * (1.f / 4096.f);
}

extern "C" void kernel_launch(void* const* d_in, const int* in_sizes, int n_in,
                              void* d_out, int out_size, void* d_ws, size_t ws_size,
                              hipStream_t stream) {
    const float* x  = (const float*)d_in[0];
    const float* w2 = (const float*)d_in[1];  const float* b2 = (const float*)d_in[2];
    const float* w3 = (const float*)d_in[3];  const float* b3 = (const float*)d_in[4];
    const float* w4 = (const float*)d_in[5];  const float* b4 = (const float*)d_in[6];
    const float* w5 = (const float*)d_in[7];  const float* b5 = (const float*)d_in[8];
    const float* w6 = (const float*)d_in[9];  const float* b6 = (const float*)d_in[10];
    const float* w7 = (const float*)d_in[11]; const float* b7 = (const float*)d_in[12];
    const float* wq = (const float*)d_in[13]; const float* bq = (const float*)d_in[14];
    const float* wk = (const float*)d_in[15]; const float* bk = (const float*)d_in[16];
    const float* wv = (const float*)d_in[17]; const float* bv = (const float*)d_in[18];
    const float* wat = (const float*)d_in[19]; const float* bat = (const float*)d_in[20];
    const float* wm = (const float*)d_in[21];  const float* bm = (const float*)d_in[22];

    float* ws = (float*)d_ws;
    float* qb = ws + WS_Q;
    float* kT = ws + WS_KT;
    float* vb = ws + WS_V;
    float* lg = ws + WS_LG;
    float* out = (float*)d_out;

    hipLaunchKernelGGL(featqkv_kernel, dim3(NB * NN / SEQ_PER_BLOCK), dim3(256), 0, stream,
                       x, w2, b2, w3, b3, w4, b4, w5, b5, w6, b6, w7, b7,
                       wq, bq, wk, bk, wv, bv, qb, kT, vb);
    hipLaunchKernelGGL(attn_kernel, dim3(NB * NN / 4), dim3(256), 0, stream,
                       qb, kT, vb, wat, bat, wm, bm, out + 8, lg);
    hipLaunchKernelGGL(pool_kernel, dim3(8), dim3(256), 0, stream, lg, out);
}

// Round 9
// 257.562 us; speedup vs baseline: 1.2270x; 1.2270x over previous
//
#include <hip/hip_runtime.h>
#include <math.h>

#define NB 4
#define NN 4096
#define KSEL 204
#define NBINS 512
#define CANDN 256
#define QKSCALE 0.31622776601683794f

// workspace layout in floats
#define WS_Q 0
#define WS_KT (NB * NN * 10)       // 163840
#define WS_V (2 * NB * NN * 10)    // 327680
#define WS_LG (3 * NB * NN * 10)   // 491520  (+ NB*NN*2 = 32768)

#define SEQ_PER_BLOCK 16

// kT layout: [B][10][N] row-major (the [B][N/64][10][64] variant broke L2
// write-combining of out_probs -> 14x WRITE_SIZE; keep row-major).
// attn structure: R0's 4-waves-per-row (VGPR<=64, Occ 80%+). R4 (2 rows/blk,
// Occ 43%) and R7 (1 wave/row, Occ 22%) both LOST despite less VALU work:
// duration tracks occupancy. Only occupancy-preserving trims allowed here.

__global__ __launch_bounds__(256) void featqkv_kernel(
    const float* __restrict__ x,
    const float* __restrict__ w2, const float* __restrict__ b2,
    const float* __restrict__ w3, const float* __restrict__ b3,
    const float* __restrict__ w4, const float* __restrict__ b4,
    const float* __restrict__ w5, const float* __restrict__ b5,
    const float* __restrict__ w6, const float* __restrict__ b6,
    const float* __restrict__ w7, const float* __restrict__ b7,
    const float* __restrict__ wq, const float* __restrict__ bq,
    const float* __restrict__ wk, const float* __restrict__ bk,
    const float* __restrict__ wv, const float* __restrict__ bv,
    float* __restrict__ q_out, float* __restrict__ kT_out, float* __restrict__ v_out)
{
    __shared__ __align__(16) float xs[SEQ_PER_BLOCK * 360];
    __shared__ float wpad[14 * 105];   // zero-padded to 7 taps: [ch][c=15][j=7]
    __shared__ float bconv[14];
    __shared__ float wqkv[420];
    __shared__ float bqkv[30];
    __shared__ float feats[SEQ_PER_BLOCK * 14];

    const int t = threadIdx.x;
    const int g0 = blockIdx.x * SEQ_PER_BLOCK;

    // ---- stage x as float4 ----
    {
        const float4* xg4 = reinterpret_cast<const float4*>(x + (size_t)g0 * 360);
        float4* xs4 = reinterpret_cast<float4*>(xs);
        for (int i = t; i < SEQ_PER_BLOCK * 90; i += 256) xs4[i] = xg4[i];
    }

    // ---- stage conv weights, zero-padded to uniform 7 taps ----
    for (int i = t; i < 14 * 105; i += 256) {
        const int ch = i / 105;
        const int r = i - ch * 105;
        const int c = r / 7;
        const int j = r - (r / 7) * 7;
        float val = 0.f;
        if (ch < 3)       { if (j < 2) val = w2[ch * 30 + c * 2 + j]; }
        else if (ch < 6)  { if (j < 3) val = w3[(ch - 3) * 45 + c * 3 + j]; }
        else if (ch < 9)  { if (j < 4) val = w4[(ch - 6) * 60 + c * 4 + j]; }
        else if (ch < 11) { if (j < 5) val = w5[(ch - 9) * 75 + c * 5 + j]; }
        else if (ch < 13) { if (j < 6) val = w6[(ch - 11) * 90 + c * 6 + j]; }
        else              { val = w7[c * 7 + j]; }
        wpad[i] = val;
    }
    if (t < 3) bconv[t] = b2[t];
    else if (t < 6) bconv[t] = b3[t - 3];
    else if (t < 9) bconv[t] = b4[t - 6];
    else if (t < 11) bconv[t] = b5[t - 9];
    else if (t < 13) bconv[t] = b6[t - 11];
    else if (t == 13) bconv[t] = b7[0];
    for (int i = t; i < 140; i += 256) wqkv[i] = wq[i];
    for (int i = t; i < 140; i += 256) wqkv[140 + i] = wk[i];
    for (int i = t; i < 140; i += 256) wqkv[280 + i] = wv[i];
    if (t < 10) bqkv[t] = bq[t];
    else if (t < 20) bqkv[t] = bk[t - 10];
    else if (t < 30) bqkv[t] = bv[t - 20];
    __syncthreads();

    const int seq = t >> 4;
    const int wkr = t & 15;

    if (wkr < 14) {
        const int ch = wkr;
        int T;
        if (ch < 3) T = 23; else if (ch < 6) T = 22; else if (ch < 9) T = 21;
        else if (ch < 11) T = 20; else if (ch < 13) T = 19; else T = 18;

        float acc[23];
#pragma unroll
        for (int u = 0; u < 23; u++) acc[u] = 0.f;
        const float* xrow = &xs[seq * 360];
        const float* wrow = &wpad[ch * 105];
        for (int c = 0; c < 15; c++) {
            float xr[30];
            const float4* xp = reinterpret_cast<const float4*>(xrow + c * 24);
#pragma unroll
            for (int u4 = 0; u4 < 6; u4++) {
                const float4 xv = xp[u4];
                xr[u4 * 4 + 0] = xv.x; xr[u4 * 4 + 1] = xv.y;
                xr[u4 * 4 + 2] = xv.z; xr[u4 * 4 + 3] = xv.w;
            }
#pragma unroll
            for (int u = 24; u < 30; u++) xr[u] = 0.f;
#pragma unroll
            for (int j = 0; j < 7; j++) {
                const float wv_ = wrow[c * 7 + j];
#pragma unroll
                for (int tt = 0; tt < 23; tt++)
                    acc[tt] = fmaf(xr[tt + j], wv_, acc[tt]);
            }
        }
        float m = -3.0e38f;
#pragma unroll
        for (int tt = 0; tt < 23; tt++)
            if (tt < T) m = fmaxf(m, acc[tt]);
        feats[seq * 14 + ch] = fmaxf(m + bconv[ch], 0.f);
    }
    __syncthreads();

    const int g = g0 + seq;
    const int b_ = g >> 12;
    const int n_ = g & 4095;
    for (int o = wkr; o < 30; o += 16) {
        const int type = o / 10;
        const int comp = o % 10;
        const float* wrow = &wqkv[type * 140 + comp * 14];
        const float* frow = &feats[seq * 14];
        float a = bqkv[type * 10 + comp];
#pragma unroll
        for (int ii = 0; ii < 14; ii++) a = fmaf(frow[ii], wrow[ii], a);
        if (type == 0) q_out[(size_t)g * 10 + comp] = a;
        else if (type == 1) kT_out[((size_t)b_ * 10 + comp) * NN + n_] = a;
        else v_out[(size_t)g * 10 + comp] = a;
    }
}

__device__ __forceinline__ float dec_key(unsigned int k) {
    return (k & 0x80000000u) ? __uint_as_float(k ^ 0x80000000u)
                             : __uint_as_float(~k);
}
__device__ __forceinline__ unsigned int enc_key(float s) {
    unsigned int u = __float_as_uint(s);
    return (u & 0x80000000u) ? ~u : (u | 0x80000000u);
}

// 256 threads / 1 row per block (R0 structure). Scores in registers;
// linear-histogram rank. Bins register-cached between P2 and P4.
__global__ __launch_bounds__(256, 8) void attn_kernel(
    const float* __restrict__ qbuf, const float* __restrict__ kTbuf,
    const float* __restrict__ vbuf,
    const float* __restrict__ w_attn, const float* __restrict__ b_attn,
    const float* __restrict__ w_mil, const float* __restrict__ b_mil,
    float* __restrict__ out_probs, float* __restrict__ logits)
{
    __shared__ unsigned int base_[NBINS];   // counts -> suffix-above (pristine)
    __shared__ unsigned int bc_[NBINS];     // mutable scatter counters
    __shared__ unsigned long long cand[CANDN];
    __shared__ float hpart[4], lpart[4], fpart[4];
    __shared__ unsigned int wtot[4];
    __shared__ float ctxp[40];
    __shared__ float ctx_sh[10];
    __shared__ float attn_sh[14];

    const int t = threadIdx.x;
    const int lane = t & 63;
    const int w = t >> 6;
    const int row = blockIdx.x;
    const int b_ = row >> 12;

    // ---- P1: scores (registers) + block min/max ----
    float q0, q1, q2, q3, q4, q5, q6, q7, q8, q9;
    {
        const float* qp = qbuf + (size_t)row * 10;
        q0 = qp[0]; q1 = qp[1]; q2 = qp[2]; q3 = qp[3]; q4 = qp[4];
        q5 = qp[5]; q6 = qp[6]; q7 = qp[7]; q8 = qp[8]; q9 = qp[9];
    }
    const float* kTb = kTbuf + (size_t)b_ * 10 * NN;
    float sc[16];
    float vhi = -1e30f, vlo = 1e30f;
#pragma unroll
    for (int i = 0; i < 4; i++) {
        float4 a0 = make_float4(0.f, 0.f, 0.f, 0.f);
#pragma unroll
        for (int c = 0; c < 10; c++) {
            const float qc = (c == 0) ? q0 : (c == 1) ? q1 : (c == 2) ? q2 : (c == 3) ? q3 :
                             (c == 4) ? q4 : (c == 5) ? q5 : (c == 6) ? q6 : (c == 7) ? q7 :
                             (c == 8) ? q8 : q9;
            const float4 kv = reinterpret_cast<const float4*>(kTb + c * NN)[i * 256 + t];
            a0.x = fmaf(qc, kv.x, a0.x);
            a0.y = fmaf(qc, kv.y, a0.y);
            a0.z = fmaf(qc, kv.z, a0.z);
            a0.w = fmaf(qc, kv.w, a0.w);
        }
        sc[i * 4 + 0] = a0.x; sc[i * 4 + 1] = a0.y;
        sc[i * 4 + 2] = a0.z; sc[i * 4 + 3] = a0.w;
        vhi = fmaxf(vhi, fmaxf(fmaxf(a0.x, a0.y), fmaxf(a0.z, a0.w)));
        vlo = fminf(vlo, fminf(fminf(a0.x, a0.y), fminf(a0.z, a0.w)));
    }
#pragma unroll
    for (int off = 32; off > 0; off >>= 1) {
        vhi = fmaxf(vhi, __shfl_xor(vhi, off));
        vlo = fminf(vlo, __shfl_xor(vlo, off));
    }
    if (lane == 0) { hpart[w] = vhi; lpart[w] = vlo; }
    // zero hist + cand under same barrier
    base_[2 * t] = 0u; base_[2 * t + 1] = 0u;
    cand[t] = 0ULL;
    __syncthreads();
    const float hi = fmaxf(fmaxf(hpart[0], hpart[1]), fmaxf(hpart[2], hpart[3]));
    const float lo = fminf(fminf(lpart[0], lpart[1]), fminf(lpart[2], lpart[3]));
    const bool degen = (hi <= lo);

    float pv = 0.f;
    int jj = 0, p = KSEL;
    bool selected = false;
    const float smax = hi * QKSCALE;

    if (!degen) {
        const float scale = (float)(NBINS - 1) / (hi - lo);

        // ---- P2: 512-bin linear histogram (bins cached in registers) ----
        int bins[16];
#pragma unroll
        for (int i = 0; i < 16; i++) {
            const int bin = (int)fminf((sc[i] - lo) * scale, (float)(NBINS - 1));
            bins[i] = bin;
            atomicAdd(&base_[bin], 1u);
        }
        __syncthreads();

        // ---- P3: suffix scan (2 bins/thread) -> base (pristine) + bc (mutable) ----
        {
            const unsigned int c0 = base_[2 * t];
            const unsigned int c1 = base_[2 * t + 1];
            const unsigned int T_ = c0 + c1;
            unsigned int acc = T_;
#pragma unroll
            for (int off = 1; off < 64; off <<= 1) {
                unsigned int o = __shfl_down(acc, off);
                if (lane + off < 64) acc += o;
            }
            if (lane == 0) wtot[w] = acc;
            __syncthreads();
            unsigned int tail = 0u;
#pragma unroll
            for (int w2 = 1; w2 < 4; w2++) if (w2 > w) tail += wtot[w2];
            const unsigned int A = (acc - T_) + tail;   // keys in bins > 2t+1
            base_[2 * t + 1] = A;
            base_[2 * t] = A + c1;
            bc_[2 * t + 1] = A;
            bc_[2 * t] = A + c1;
        }
        __syncthreads();

        // ---- P4: scatter candidate keys (bins whose base < KSEL) ----
#pragma unroll
        for (int i = 0; i < 16; i++) {
            const int bin = bins[i];
            const unsigned int bs = base_[bin];
            if (bs < KSEL) {
                const unsigned int pos = atomicAdd(&bc_[bin], 1u);
                if (pos < CANDN) {
                    const int j = (i >> 2) * 1024 + t * 4 + (i & 3);
                    cand[pos] = (((unsigned long long)enc_key(sc[i])) << 16)
                              | (unsigned long long)(4095 - j);
                }
            }
        }
        __syncthreads();

        // ---- P5: within-bin rank -> exact sorted position ----
        const unsigned long long mine = cand[t];
        if (mine != 0ULL) {
            const float s = dec_key((unsigned int)(mine >> 16));
            const int bin = (int)fminf((s - lo) * scale, (float)(NBINS - 1));
            const unsigned int bs = base_[bin];
            // bin's keys occupy [base[bin], base[bin-1])
            unsigned int e2 = (bin > 0) ? base_[bin - 1] : 4096u;
            if (e2 > CANDN) e2 = CANDN;
            unsigned int rank = 0;
            for (unsigned int s2 = bs; s2 < e2; s2++)
                rank += (cand[s2] > mine) ? 1u : 0u;
            const unsigned int pp = bs + rank;
            if (pp < KSEL) {
                selected = true;
                p = (int)pp;
                jj = 4095 - (int)(mine & 0xFFFFu);
                pv = expf(s * QKSCALE - smax);
            }
        }
    } else {
        // all scores equal: top-K = lowest indices, uniform softmax
        if (t < KSEL) {
            selected = true;
            p = t;
            jj = t;
            pv = 1.f;
        }
    }

    // ---- P6: softmax denom ----
    float dsum = pv;
#pragma unroll
    for (int off = 32; off > 0; off >>= 1) dsum += __shfl_xor(dsum, off);
    if (lane == 0) fpart[w] = dsum;
    __syncthreads();
    const float inv = 1.f / (fpart[0] + fpart[1] + fpart[2] + fpart[3]);

    // ---- P7: probs out + ctx ----
    float cx0 = 0.f, cx1 = 0.f, cx2 = 0.f, cx3 = 0.f, cx4 = 0.f;
    float cx5 = 0.f, cx6 = 0.f, cx7 = 0.f, cx8 = 0.f, cx9 = 0.f;
    if (selected) {
        const float pn = pv * inv;
        out_probs[(size_t)row * KSEL + p] = pn;
        const float* vr = vbuf + ((size_t)b_ * NN + (size_t)jj) * 10;
        const float2 v01 = reinterpret_cast<const float2*>(vr)[0];
        const float2 v23 = reinterpret_cast<const float2*>(vr)[1];
        const float2 v45 = reinterpret_cast<const float2*>(vr)[2];
        const float2 v67 = reinterpret_cast<const float2*>(vr)[3];
        const float2 v89 = reinterpret_cast<const float2*>(vr)[4];
        cx0 = pn * v01.x; cx1 = pn * v01.y;
        cx2 = pn * v23.x; cx3 = pn * v23.y;
        cx4 = pn * v45.x; cx5 = pn * v45.y;
        cx6 = pn * v67.x; cx7 = pn * v67.y;
        cx8 = pn * v89.x; cx9 = pn * v89.y;
    }
#pragma unroll
    for (int off = 32; off > 0; off >>= 1) {
        cx0 += __shfl_xor(cx0, off); cx1 += __shfl_xor(cx1, off);
        cx2 += __shfl_xor(cx2, off); cx3 += __shfl_xor(cx3, off);
        cx4 += __shfl_xor(cx4, off); cx5 += __shfl_xor(cx5, off);
        cx6 += __shfl_xor(cx6, off); cx7 += __shfl_xor(cx7, off);
        cx8 += __shfl_xor(cx8, off); cx9 += __shfl_xor(cx9, off);
    }
    if (lane == 0) {
        ctxp[w * 10 + 0] = cx0; ctxp[w * 10 + 1] = cx1; ctxp[w * 10 + 2] = cx2;
        ctxp[w * 10 + 3] = cx3; ctxp[w * 10 + 4] = cx4; ctxp[w * 10 + 5] = cx5;
        ctxp[w * 10 + 6] = cx6; ctxp[w * 10 + 7] = cx7; ctxp[w * 10 + 8] = cx8;
        ctxp[w * 10 + 9] = cx9;
    }
    __syncthreads();
    if (t < 10) ctx_sh[t] = ctxp[t] + ctxp[10 + t] + ctxp[20 + t] + ctxp[30 + t];
    __syncthreads();

    // ---- P8: attn projection + mil logits ----
    if (t < 14) {
        float a = b_attn[t];
#pragma unroll
        for (int d = 0; d < 10; d++) a = fmaf(ctx_sh[d], w_attn[t * 10 + d], a);
        attn_sh[t] = a;
    }
    __syncthreads();
    if (t < 2) {
        float lg = b_mil[t];
#pragma unroll
        for (int ii = 0; ii < 14; ii++) lg = fmaf(attn_sh[ii], w_mil[t * 14 + ii], lg);
        logits[(size_t)row * 2 + t] = lg;
    }
}

__global__ __launch_bounds__(256) void pool_kernel(
    const float* __restrict__ logits, float* __restrict__ out)
{
    __shared__ float red[256];
    const int t = threadIdx.x;
    const int bc = blockIdx.x;
    const int b_ = bc >> 1;
    const int c_ = bc & 1;
    float a = 0.f;
    for (int n2 = t; n2 < NN; n2 += 256)
        a += logits[((size_t)b_ * NN + n2) * 2 + c_];
    red[t] = a;
    __syncthreads();
    for (int off = 128; off > 0; off >>= 1) {
        if (t < off) red[t] += red[t + off];
        __syncthreads();
    }
    if (t == 0) out[bc] = red[0] * (1.f / 4096.f);
}

extern "C" void kernel_launch(void* const* d_in, const int* in_sizes, int n_in,
                              void* d_out, int out_size, void* d_ws, size_t ws_size,
                              hipStream_t stream) {
    const float* x  = (const float*)d_in[0];
    const float* w2 = (const float*)d_in[1];  const float* b2 = (const float*)d_in[2];
    const float* w3 = (const float*)d_in[3];  const float* b3 = (const float*)d_in[4];
    const float* w4 = (const float*)d_in[5];  const float* b4 = (const float*)d_in[6];
    const float* w5 = (const float*)d_in[7];  const float* b5 = (const float*)d_in[8];
    const float* w6 = (const float*)d_in[9];  const float* b6 = (const float*)d_in[10];
    const float* w7 = (const float*)d_in[11]; const float* b7 = (const float*)d_in[12];
    const float* wq = (const float*)d_in[13]; const float* bq = (const float*)d_in[14];
    const float* wk = (const float*)d_in[15]; const float* bk = (const float*)d_in[16];
    const float* wv = (const float*)d_in[17]; const float* bv = (const float*)d_in[18];
    const float* wat = (const float*)d_in[19]; const float* bat = (const float*)d_in[20];
    const float* wm = (const float*)d_in[21];  const float* bm = (const float*)d_in[22];

    float* ws = (float*)d_ws;
    float* qb = ws + WS_Q;
    float* kT = ws + WS_KT;
    float* vb = ws + WS_V;
    float* lg = ws + WS_LG;
    float* out = (float*)d_out;

    hipLaunchKernelGGL(featqkv_kernel, dim3(NB * NN / SEQ_PER_BLOCK), dim3(256), 0, stream,
                       x, w2, b2, w3, b3, w4, b4, w5, b5, w6, b6, w7, b7,
                       wq, bq, wk, bk, wv, bv, qb, kT, vb);
    hipLaunchKernelGGL(attn_kernel, dim3(NB * NN), dim3(256), 0, stream,
                       qb, kT, vb, wat, bat, wm, bm, out + 8, lg);
    hipLaunchKernelGGL(pool_kernel, dim3(8), dim3(256), 0, stream, lg, out);
}